// Round 4
// baseline (47.289 us; speedup 1.0000x reference)
//
#include <hip/hip_runtime.h>

// Problem constants (from reference setup_inputs)
constexpr int Bn = 256;
constexpr int Nn = 16384;
constexpr int Hh = 96;
constexpr int Ww = 96;

constexpr int THREADS = 1024;
constexpr int CHUNKS  = 2;                 // blocks per batch
constexpr int PS  = 100;                   // padded row stride (floats)
constexpr int PSZ = PS * PS;               // 10000 floats per padded map (40 KB)
constexpr int PER_THREAD = Nn / CHUNKS / THREADS;   // 8 corners per thread

// Plain zero-padded fp32 maps in LDS (4B entries -> all 32 banks usable).
// Adjacent-column reads merge to ds_read2_b32. 80 KB/block -> 2 blocks/CU.
__global__ __launch_bounds__(THREADS, 8)
void geo_kernel(const float* __restrict__ corners,
                const float* __restrict__ edge,
                const float* __restrict__ mask,
                double* __restrict__ acc,      // [0]=edge sum, [1]=mask sum, [2]=counter
                float* __restrict__ out)
{
    __shared__ float sE[PSZ];
    __shared__ float sM[PSZ];
    __shared__ float redE[THREADS / 64];
    __shared__ float redM[THREADS / 64];

    const int b     = blockIdx.x >> 1;     // CHUNKS == 2
    const int chunk = blockIdx.x & 1;
    const int tid   = threadIdx.x;

    // --- batch-load this thread's corners (independent coalesced loads) ---
    const float2* c2 =
        (const float2*)(corners + (size_t)b * Nn * 2) + (size_t)chunk * (Nn / CHUNKS);
    float2 cc[PER_THREAD];
#pragma unroll
    for (int j = 0; j < PER_THREAD; ++j)
        cc[j] = c2[tid + j * THREADS];

    // --- zero both padded buffers (float4) ---
    {
        const float4 z4 = make_float4(0.f, 0.f, 0.f, 0.f);
        float4* e4 = (float4*)sE;
        float4* m4 = (float4*)sM;
        for (int i = tid; i < PSZ / 4; i += THREADS) {
            e4[i] = z4;
            m4[i] = z4;
        }
    }
    __syncthreads();

    // --- fill interior ---
    {
        const float2* eg = (const float2*)(edge + (size_t)b * Hh * Ww);
        const float2* mg = (const float2*)(mask + (size_t)b * Hh * Ww);
        for (int i = tid; i < (Ww / 2) * Hh; i += THREADS) {
            int r = i / (Ww / 2);
            int j = i - r * (Ww / 2);
            int dst = (r + 2) * PS + 2 + 2 * j;
            *(float2*)&sE[dst] = eg[i];
            *(float2*)&sM[dst] = mg[i];
        }
    }
    __syncthreads();

    // --- per-corner work ---
    float eAcc = 0.f, mAcc = 0.f;
#pragma unroll
    for (int j = 0; j < PER_THREAD; ++j) {
        float2 c = cc[j];
        // ix = ((gx+1)*W - 1)*0.5 with gx = 2*cx - 1  ==>  ix = 96*cx - 0.5
        float ix = fmaf(c.x, 96.f, -0.5f);
        float iy = fmaf(c.y, 96.f, -0.5f);
        float x0f = floorf(ix), y0f = floorf(iy);
        float wx = ix - x0f, wy = iy - y0f;
        int x0 = (int)x0f, y0 = (int)y0f;

        // edge: 4x4 patch rows y0-1..y0+2, cols x0-1..x0+2
        // padded addr of pixel (x,y) = (y+2)*PS + (x+2)
        int cb = (y0 + 1) * PS + (x0 + 1);
        float p00 = sE[cb + 0],      p01 = sE[cb + 1],
              p02 = sE[cb + 2],      p03 = sE[cb + 3];
        float p10 = sE[cb + PS],     p11 = sE[cb + PS + 1],
              p12 = sE[cb + PS + 2], p13 = sE[cb + PS + 3];
        float p20 = sE[cb + 2*PS],     p21 = sE[cb + 2*PS + 1],
              p22 = sE[cb + 2*PS + 2], p23 = sE[cb + 2*PS + 3];
        float p30 = sE[cb + 3*PS],     p31 = sE[cb + 3*PS + 1],
              p32 = sE[cb + 3*PS + 2], p33 = sE[cb + 3*PS + 3];
        // mask: 2x2 at (x0..x0+1, y0..y0+1)
        int mb = (y0 + 2) * PS + (x0 + 2);
        float q0 = sM[mb],      q1 = sM[mb + 1],
              q2 = sM[mb + PS], q3 = sM[mb + PS + 1];

        float h[4][3];
        h[0][0] = fmaf(wx, p01 - p00, p00);
        h[0][1] = fmaf(wx, p02 - p01, p01);
        h[0][2] = fmaf(wx, p03 - p02, p02);
        h[1][0] = fmaf(wx, p11 - p10, p10);
        h[1][1] = fmaf(wx, p12 - p11, p11);
        h[1][2] = fmaf(wx, p13 - p12, p12);
        h[2][0] = fmaf(wx, p21 - p20, p20);
        h[2][1] = fmaf(wx, p22 - p21, p21);
        h[2][2] = fmaf(wx, p23 - p22, p22);
        h[3][0] = fmaf(wx, p31 - p30, p30);
        h[3][1] = fmaf(wx, p32 - p31, p31);
        h[3][2] = fmaf(wx, p33 - p32, p32);

        float best = fmaf(wy, h[1][0] - h[0][0], h[0][0]);
#pragma unroll
        for (int r = 0; r < 3; ++r) {
#pragma unroll
            for (int k = 0; k < 3; ++k) {
                if (r == 0 && k == 0) continue;
                float s = fmaf(wy, h[r + 1][k] - h[r][k], h[r][k]);
                best = fmaxf(best, s);
            }
        }
        eAcc += best;

        float t = fmaf(wx, q1 - q0, q0);
        float u = fmaf(wx, q3 - q2, q2);
        float mm = fmaf(wy, u - t, t);
        float dd = mm - 0.5f;
        mAcc = fmaf(dd, dd, mAcc);
    }

    // --- reduce: wave shuffle, cross-wave via LDS ---
#pragma unroll
    for (int off = 32; off > 0; off >>= 1) {
        eAcc += __shfl_xor(eAcc, off);
        mAcc += __shfl_xor(mAcc, off);
    }
    const int wv = tid >> 6;
    const int ln = tid & 63;
    if (ln == 0) { redE[wv] = eAcc; redM[wv] = mAcc; }
    __syncthreads();

    if (tid == 0) {
        float e = 0.f, m = 0.f;
#pragma unroll
        for (int w = 0; w < THREADS / 64; ++w) { e += redE[w]; m += redM[w]; }
        atomicAdd(&acc[0], (double)e);
        atomicAdd(&acc[1], (double)m);
        __threadfence();
        unsigned old = atomicAdd((unsigned*)&acc[2], 1u);
        if (old == (unsigned)(gridDim.x - 1)) {
            double se = atomicAdd(&acc[0], 0.0);
            double sm = atomicAdd(&acc[1], 0.0);
            const double inv = 1.0 / (double)((long long)Bn * (long long)Nn);
            double edge_loss = 1.0 - se * inv;
            double mask_loss = sm * inv;
            out[0] = (float)(edge_loss + 2.0 * mask_loss);
        }
    }
}

extern "C" void kernel_launch(void* const* d_in, const int* in_sizes, int n_in,
                              void* d_out, int out_size, void* d_ws, size_t ws_size,
                              hipStream_t stream)
{
    const float* corners = (const float*)d_in[0];
    const float* edge    = (const float*)d_in[1];
    const float* mask    = (const float*)d_in[2];
    float* out  = (float*)d_out;
    double* acc = (double*)d_ws;

    hipMemsetAsync(acc, 0, 32, stream);   // 2 doubles + counter
    geo_kernel<<<Bn * CHUNKS, THREADS, 0, stream>>>(corners, edge, mask, acc, out);
}

// Round 5
// 45.744 us; speedup vs baseline: 1.0338x; 1.0338x over previous
//
#include <hip/hip_runtime.h>
#include <hip/hip_fp16.h>

// Problem constants (from reference setup_inputs)
constexpr int Bn = 256;
constexpr int Nn = 16384;
constexpr int Hh = 96;
constexpr int Ww = 96;

constexpr int THREADS = 1024;
constexpr int CHUNKS  = 2;                 // blocks per batch
constexpr int PS  = 100;                   // packed entries per padded row
constexpr int PSZ = PS * PS;               // 10000 entries x 4B = 40 KB per map
constexpr int PER_THREAD = Nn / CHUNKS / THREADS;   // 8 corners per thread

// LDS layout: entry[e] = (half(pad[e]), half(pad[e+1])) per row, where pad is
// the zero-padded (2 each side) map row. Any 4-pixel row segment = 2 entries
// 2 apart -> one ds_read2_b32. Edge patch = 4 instr, mask 2x2 = 1 instr.
__global__ __launch_bounds__(THREADS, 8)
void geo_kernel(const float* __restrict__ corners,
                const float* __restrict__ edge,
                const float* __restrict__ mask,
                double* __restrict__ acc,      // [0]=edge sum, [1]=mask sum, [2]=counter
                float* __restrict__ out)
{
    __shared__ alignas(16) __half2 sE[PSZ];
    __shared__ alignas(16) __half2 sM[PSZ];
    __shared__ float redE[THREADS / 64];
    __shared__ float redM[THREADS / 64];

    const int b     = blockIdx.x >> 1;     // CHUNKS == 2
    const int chunk = blockIdx.x & 1;
    const int tid   = threadIdx.x;

    // --- batch-load this thread's corners (independent coalesced loads) ---
    const float2* c2 =
        (const float2*)(corners + (size_t)b * Nn * 2) + (size_t)chunk * (Nn / CHUNKS);
    float2 cc[PER_THREAD];
#pragma unroll
    for (int j = 0; j < PER_THREAD; ++j)
        cc[j] = c2[tid + j * THREADS];

    // --- zero both packed buffers (float4 = 4 entries) ---
    {
        const float4 z4 = make_float4(0.f, 0.f, 0.f, 0.f);
        float4* e4 = (float4*)sE;
        float4* m4 = (float4*)sM;
        for (int i = tid; i < PSZ / 4; i += THREADS) {
            e4[i] = z4;
            m4[i] = z4;
        }
    }
    __syncthreads();

    // --- fill interior with packed fp16 pairs ---
    // thread i handles image row r, float2 chunk j (pixels 2j, 2j+1):
    //   entry[(r+2)*PS + 2j+2] = (P[2j],  P[2j+1])
    //   entry[(r+2)*PS + 2j+3] = (P[2j+1],P[2j+2])   (0 past the edge)
    //   j==0 also writes entry col 1 = (0, P[0])
    {
        const float* eb = edge + (size_t)b * Hh * Ww;
        const float* mb = mask + (size_t)b * Hh * Ww;
        for (int i = tid; i < Hh * (Ww / 2); i += THREADS) {
            int r = i / (Ww / 2);
            int j = i - r * (Ww / 2);
            const float* erow = eb + r * Ww;
            const float* mrow = mb + r * Ww;
            float2 ae = *(const float2*)(erow + 2 * j);
            float2 am = *(const float2*)(mrow + 2 * j);
            float ne = (2 * j + 2 < Ww) ? erow[2 * j + 2] : 0.f;
            float nm = (2 * j + 2 < Ww) ? mrow[2 * j + 2] : 0.f;
            int base = (r + 2) * PS + 2 * j + 2;
            sE[base]     = __float22half2_rn(make_float2(ae.x, ae.y));
            sE[base + 1] = __float22half2_rn(make_float2(ae.y, ne));
            sM[base]     = __float22half2_rn(make_float2(am.x, am.y));
            sM[base + 1] = __float22half2_rn(make_float2(am.y, nm));
            if (j == 0) {
                sE[(r + 2) * PS + 1] = __float22half2_rn(make_float2(0.f, ae.x));
                sM[(r + 2) * PS + 1] = __float22half2_rn(make_float2(0.f, am.x));
            }
        }
    }
    __syncthreads();

    // --- per-corner work: 5 LDS instructions per corner ---
    float eAcc = 0.f, mAcc = 0.f;
#pragma unroll
    for (int j = 0; j < PER_THREAD; ++j) {
        float2 c = cc[j];
        // ix = ((gx+1)*W - 1)*0.5 with gx = 2*cx - 1  ==>  ix = 96*cx - 0.5
        float ix = fmaf(c.x, 96.f, -0.5f);
        float iy = fmaf(c.y, 96.f, -0.5f);
        float x0f = floorf(ix), y0f = floorf(iy);
        float wx = ix - x0f, wy = iy - y0f;
        int x0 = (int)x0f, y0 = (int)y0f;

        // edge patch rows: pad rows y0+1..y0+4, entry cols x0+1 and x0+3
        int cb = (y0 + 1) * PS + (x0 + 1);
        __half2 e00 = sE[cb],          e01 = sE[cb + 2];
        __half2 e10 = sE[cb + PS],     e11 = sE[cb + PS + 2];
        __half2 e20 = sE[cb + 2 * PS], e21 = sE[cb + 2 * PS + 2];
        __half2 e30 = sE[cb + 3 * PS], e31 = sE[cb + 3 * PS + 2];
        // mask 2x2: entry col x0+2, pad rows y0+2, y0+3
        int mb = (y0 + 2) * PS + (x0 + 2);
        __half2 mm0 = sM[mb], mm1 = sM[mb + PS];

        float2 r00 = __half22float2(e00), r01 = __half22float2(e01);
        float2 r10 = __half22float2(e10), r11 = __half22float2(e11);
        float2 r20 = __half22float2(e20), r21 = __half22float2(e21);
        float2 r30 = __half22float2(e30), r31 = __half22float2(e31);

        float h[4][3];
        h[0][0] = fmaf(wx, r00.y - r00.x, r00.x);
        h[0][1] = fmaf(wx, r01.x - r00.y, r00.y);
        h[0][2] = fmaf(wx, r01.y - r01.x, r01.x);
        h[1][0] = fmaf(wx, r10.y - r10.x, r10.x);
        h[1][1] = fmaf(wx, r11.x - r10.y, r10.y);
        h[1][2] = fmaf(wx, r11.y - r11.x, r11.x);
        h[2][0] = fmaf(wx, r20.y - r20.x, r20.x);
        h[2][1] = fmaf(wx, r21.x - r20.y, r20.y);
        h[2][2] = fmaf(wx, r21.y - r21.x, r21.x);
        h[3][0] = fmaf(wx, r30.y - r30.x, r30.x);
        h[3][1] = fmaf(wx, r31.x - r30.y, r30.y);
        h[3][2] = fmaf(wx, r31.y - r31.x, r31.x);

        float best = fmaf(wy, h[1][0] - h[0][0], h[0][0]);
#pragma unroll
        for (int r = 0; r < 3; ++r) {
#pragma unroll
            for (int k = 0; k < 3; ++k) {
                if (r == 0 && k == 0) continue;
                float s = fmaf(wy, h[r + 1][k] - h[r][k], h[r][k]);
                best = fmaxf(best, s);
            }
        }
        eAcc += best;

        float2 q0 = __half22float2(mm0);
        float2 q1 = __half22float2(mm1);
        float t = fmaf(wx, q0.y - q0.x, q0.x);
        float u = fmaf(wx, q1.y - q1.x, q1.x);
        float m = fmaf(wy, u - t, t);
        float d = m - 0.5f;
        mAcc = fmaf(d, d, mAcc);
    }

    // --- reduce: wave shuffle, cross-wave via LDS ---
#pragma unroll
    for (int off = 32; off > 0; off >>= 1) {
        eAcc += __shfl_xor(eAcc, off);
        mAcc += __shfl_xor(mAcc, off);
    }
    const int wv = tid >> 6;
    const int ln = tid & 63;
    if (ln == 0) { redE[wv] = eAcc; redM[wv] = mAcc; }
    __syncthreads();

    if (tid == 0) {
        float e = 0.f, m = 0.f;
#pragma unroll
        for (int w = 0; w < THREADS / 64; ++w) { e += redE[w]; m += redM[w]; }
        atomicAdd(&acc[0], (double)e);
        atomicAdd(&acc[1], (double)m);
        __threadfence();
        unsigned old = atomicAdd((unsigned*)&acc[2], 1u);
        if (old == (unsigned)(gridDim.x - 1)) {
            double se = atomicAdd(&acc[0], 0.0);
            double sm = atomicAdd(&acc[1], 0.0);
            const double inv = 1.0 / (double)((long long)Bn * (long long)Nn);
            double edge_loss = 1.0 - se * inv;
            double mask_loss = sm * inv;
            out[0] = (float)(edge_loss + 2.0 * mask_loss);
        }
    }
}

extern "C" void kernel_launch(void* const* d_in, const int* in_sizes, int n_in,
                              void* d_out, int out_size, void* d_ws, size_t ws_size,
                              hipStream_t stream)
{
    const float* corners = (const float*)d_in[0];
    const float* edge    = (const float*)d_in[1];
    const float* mask    = (const float*)d_in[2];
    float* out  = (float*)d_out;
    double* acc = (double*)d_ws;

    hipMemsetAsync(acc, 0, 32, stream);   // 2 doubles + counter
    geo_kernel<<<Bn * CHUNKS, THREADS, 0, stream>>>(corners, edge, mask, acc, out);
}

// Round 6
// 29.405 us; speedup vs baseline: 1.6082x; 1.5556x over previous
//
#include <hip/hip_runtime.h>
#include <hip/hip_fp16.h>

// Problem constants (from reference setup_inputs)
constexpr int Bn = 256;
constexpr int Nn = 16384;
constexpr int Hh = 96;
constexpr int Ww = 96;

constexpr int THREADS = 1024;
constexpr int CHUNKS  = 2;                 // blocks per batch
constexpr int EPS = 100;                   // edge entries per padded row (dup-pair fp16)
constexpr int ESZ = 100 * 100;             // 10000 entries x 4B = 40 KB
constexpr int MPS = 50;                    // mask entries per padded row (plain fp16 pairs)
constexpr int MSZ = 100 * 50;              // 5000 entries x 4B = 20 KB
constexpr int PER_THREAD = Nn / CHUNKS / THREADS;   // 8 corners per thread

// Edge LDS: dup-pair fp16, entry[e] = (half(pad[e]), half(pad[e+1])).
//   4x4 patch = 4 x ds_read2_b32.
// Mask LDS: plain fp16 pairs, entry e of row = padded px (2e, 2e+1).
//   pixels (p,p+1) always inside entries (p>>1, (p>>1)+1) -> 1 ds_read2_b32
//   per row + cndmask select on (p&1). 2 instr per corner.
// Total 60.4 KB/block -> 2 blocks/CU with wide margin.
__global__ __launch_bounds__(THREADS, 8)
void geo_kernel(const float* __restrict__ corners,
                const float* __restrict__ edge,
                const float* __restrict__ mask,
                float2* __restrict__ partial)
{
    __shared__ alignas(16) __half2 sE[ESZ];
    __shared__ alignas(16) __half2 sM[MSZ];
    __shared__ float redE[THREADS / 64];
    __shared__ float redM[THREADS / 64];

    const int b     = blockIdx.x >> 1;     // CHUNKS == 2
    const int chunk = blockIdx.x & 1;
    const int tid   = threadIdx.x;

    // --- batch-load this thread's corners (independent coalesced loads) ---
    const float2* c2 =
        (const float2*)(corners + (size_t)b * Nn * 2) + (size_t)chunk * (Nn / CHUNKS);
    float2 cc[PER_THREAD];
#pragma unroll
    for (int j = 0; j < PER_THREAD; ++j)
        cc[j] = c2[tid + j * THREADS];

    // --- zero both buffers (float4 granularity) ---
    {
        const float4 z4 = make_float4(0.f, 0.f, 0.f, 0.f);
        float4* e4 = (float4*)sE;          // 2500 float4
        float4* m4 = (float4*)sM;          // 1250 float4
        for (int i = tid; i < 2500; i += THREADS) {
            e4[i] = z4;
            if (i < 1250) m4[i] = z4;
        }
    }
    __syncthreads();

    // --- fill interiors ---
    {
        const float* ebase = edge + (size_t)b * Hh * Ww;
        const float* mbase = mask + (size_t)b * Hh * Ww;
        for (int i = tid; i < Hh * (Ww / 2); i += THREADS) {
            int r = i / (Ww / 2);
            int j = i - r * (Ww / 2);
            const float* erow = ebase + r * Ww;
            float2 ae = *(const float2*)(erow + 2 * j);
            float ne = (2 * j + 2 < Ww) ? erow[2 * j + 2] : 0.f;
            int base = (r + 2) * EPS + 2 * j + 2;
            sE[base]     = __float22half2_rn(make_float2(ae.x, ae.y));
            sE[base + 1] = __float22half2_rn(make_float2(ae.y, ne));
            if (j == 0)
                sE[(r + 2) * EPS + 1] = __float22half2_rn(make_float2(0.f, ae.x));
            float2 am = *(const float2*)(mbase + r * Ww + 2 * j);
            sM[(r + 2) * MPS + 1 + j] = __float22half2_rn(make_float2(am.x, am.y));
        }
    }
    __syncthreads();

    // --- per-corner work: 6 LDS instructions per corner ---
    float eAcc = 0.f, mAcc = 0.f;
#pragma unroll
    for (int j = 0; j < PER_THREAD; ++j) {
        float2 c = cc[j];
        // ix = ((gx+1)*W - 1)*0.5 with gx = 2*cx - 1  ==>  ix = 96*cx - 0.5
        float ix = fmaf(c.x, 96.f, -0.5f);
        float iy = fmaf(c.y, 96.f, -0.5f);
        float x0f = floorf(ix), y0f = floorf(iy);
        float wx = ix - x0f, wy = iy - y0f;
        int x0 = (int)x0f, y0 = (int)y0f;

        // edge patch: pad rows y0+1..y0+4, entry cols x0+1 and x0+3
        int cb = (y0 + 1) * EPS + (x0 + 1);
        __half2 e00 = sE[cb],           e01 = sE[cb + 2];
        __half2 e10 = sE[cb + EPS],     e11 = sE[cb + EPS + 2];
        __half2 e20 = sE[cb + 2 * EPS], e21 = sE[cb + 2 * EPS + 2];
        __half2 e30 = sE[cb + 3 * EPS], e31 = sE[cb + 3 * EPS + 2];

        // mask 2x2: padded px p = x0+2, rows y0+2, y0+3
        int e0  = (x0 + 2) >> 1;
        int odd = x0 & 1;                  // (x0+2)&1 == x0&1
        int mb  = (y0 + 2) * MPS + e0;
        __half2 ma_lo = sM[mb],       ma_hi = sM[mb + 1];
        __half2 mc_lo = sM[mb + MPS], mc_hi = sM[mb + MPS + 1];

        float2 r00 = __half22float2(e00), r01 = __half22float2(e01);
        float2 r10 = __half22float2(e10), r11 = __half22float2(e11);
        float2 r20 = __half22float2(e20), r21 = __half22float2(e21);
        float2 r30 = __half22float2(e30), r31 = __half22float2(e31);

        float h[4][3];
        h[0][0] = fmaf(wx, r00.y - r00.x, r00.x);
        h[0][1] = fmaf(wx, r01.x - r00.y, r00.y);
        h[0][2] = fmaf(wx, r01.y - r01.x, r01.x);
        h[1][0] = fmaf(wx, r10.y - r10.x, r10.x);
        h[1][1] = fmaf(wx, r11.x - r10.y, r10.y);
        h[1][2] = fmaf(wx, r11.y - r11.x, r11.x);
        h[2][0] = fmaf(wx, r20.y - r20.x, r20.x);
        h[2][1] = fmaf(wx, r21.x - r20.y, r20.y);
        h[2][2] = fmaf(wx, r21.y - r21.x, r21.x);
        h[3][0] = fmaf(wx, r30.y - r30.x, r30.x);
        h[3][1] = fmaf(wx, r31.x - r30.y, r30.y);
        h[3][2] = fmaf(wx, r31.y - r31.x, r31.x);

        float best = fmaf(wy, h[1][0] - h[0][0], h[0][0]);
#pragma unroll
        for (int r = 0; r < 3; ++r) {
#pragma unroll
            for (int k = 0; k < 3; ++k) {
                if (r == 0 && k == 0) continue;
                float s = fmaf(wy, h[r + 1][k] - h[r][k], h[r][k]);
                best = fmaxf(best, s);
            }
        }
        eAcc += best;

        float2 qa = __half22float2(ma_lo), qb = __half22float2(ma_hi);
        float2 qc = __half22float2(mc_lo), qd = __half22float2(mc_hi);
        float l0 = odd ? qa.y : qa.x;
        float r0 = odd ? qb.x : qa.y;
        float l1 = odd ? qc.y : qc.x;
        float r1 = odd ? qd.x : qc.y;
        float t = fmaf(wx, r0 - l0, l0);
        float u = fmaf(wx, r1 - l1, l1);
        float m = fmaf(wy, u - t, t);
        float d = m - 0.5f;
        mAcc = fmaf(d, d, mAcc);
    }

    // --- reduce: wave shuffle, cross-wave via LDS, write per-block partial ---
#pragma unroll
    for (int off = 32; off > 0; off >>= 1) {
        eAcc += __shfl_xor(eAcc, off);
        mAcc += __shfl_xor(mAcc, off);
    }
    const int wv = tid >> 6;
    const int ln = tid & 63;
    if (ln == 0) { redE[wv] = eAcc; redM[wv] = mAcc; }
    __syncthreads();

    if (tid == 0) {
        float e = 0.f, m = 0.f;
#pragma unroll
        for (int w = 0; w < THREADS / 64; ++w) { e += redE[w]; m += redM[w]; }
        partial[blockIdx.x] = make_float2(e, m);
    }
}

// Final reduction over the 512 block partials; no atomics anywhere.
__global__ __launch_bounds__(512)
void geo_reduce(const float2* __restrict__ partial, float* __restrict__ out)
{
    __shared__ double rE[8];
    __shared__ double rM[8];
    const int tid = threadIdx.x;
    float2 p = partial[tid];               // 512 partials, 512 threads
    double e = (double)p.x, m = (double)p.y;
#pragma unroll
    for (int off = 32; off > 0; off >>= 1) {
        e += __shfl_xor(e, off);
        m += __shfl_xor(m, off);
    }
    if ((tid & 63) == 0) { rE[tid >> 6] = e; rM[tid >> 6] = m; }
    __syncthreads();
    if (tid == 0) {
        double se = 0.0, sm = 0.0;
#pragma unroll
        for (int w = 0; w < 8; ++w) { se += rE[w]; sm += rM[w]; }
        const double inv = 1.0 / (double)((long long)Bn * (long long)Nn);
        double edge_loss = 1.0 - se * inv;
        double mask_loss = sm * inv;
        out[0] = (float)(edge_loss + 2.0 * mask_loss);
    }
}

extern "C" void kernel_launch(void* const* d_in, const int* in_sizes, int n_in,
                              void* d_out, int out_size, void* d_ws, size_t ws_size,
                              hipStream_t stream)
{
    const float* corners = (const float*)d_in[0];
    const float* edge    = (const float*)d_in[1];
    const float* mask    = (const float*)d_in[2];
    float* out      = (float*)d_out;
    float2* partial = (float2*)d_ws;

    geo_kernel<<<Bn * CHUNKS, THREADS, 0, stream>>>(corners, edge, mask, partial);
    geo_reduce<<<1, 512, 0, stream>>>(partial, out);
}

// Round 7
// 28.971 us; speedup vs baseline: 1.6323x; 1.0150x over previous
//
#include <hip/hip_runtime.h>
#include <hip/hip_fp16.h>

// Problem constants (from reference setup_inputs)
constexpr int Bn = 256;
constexpr int Nn = 16384;
constexpr int Hh = 96;
constexpr int Ww = 96;

constexpr int THREADS = 1024;
constexpr int CHUNKS  = 2;                 // blocks per batch
constexpr int EPS = 100;                   // edge entries per padded row (dup-pair fp16)
constexpr int ESZ = 100 * 100;             // 10000 entries x 4B = 40 KB
constexpr int MPS = 50;                    // mask entries per padded row (plain fp16 pairs)
constexpr int MSZ = 100 * 50;              // 5000 entries x 4B = 20 KB
constexpr int PER_THREAD = Nn / CHUNKS / THREADS;   // 8 corners per thread

// Edge LDS: dup-pair fp16, entry[e] = (half(pad[e]), half(pad[e+1])).
//   4x4 patch = 4 x ds_read2_b32.
// Mask LDS: plain fp16 pairs. 2x2 sample = 2 x ds_read_b64 + cndmask select.
// 60.4 KB/block -> 2 blocks/CU (proven resident in R6).
// Staging: border-only zeroing, provably disjoint from interior fill ->
// zero || fill under a SINGLE barrier; corner loads hoisted to the top.
__global__ __launch_bounds__(THREADS, 8)
void geo_kernel(const float* __restrict__ corners,
                const float* __restrict__ edge,
                const float* __restrict__ mask,
                float2* __restrict__ partial)
{
    __shared__ alignas(16) __half2 sE[ESZ];
    __shared__ alignas(16) __half2 sM[MSZ];
    __shared__ float redE[THREADS / 64];
    __shared__ float redM[THREADS / 64];

    const int b     = blockIdx.x >> 1;     // CHUNKS == 2
    const int chunk = blockIdx.x & 1;
    const int tid   = threadIdx.x;

    // --- hoisted corner loads: 4 coalesced float4 (= 8 corners) per thread ---
    const float4* c4 =
        (const float4*)(corners + (size_t)b * Nn * 2 + (size_t)chunk * (Nn / CHUNKS) * 2);
    float4 cc[4];
#pragma unroll
    for (int k = 0; k < 4; ++k)
        cc[k] = c4[k * THREADS + tid];     // 16 KB contiguous per wave-instr

    // --- zero ONLY the border entries (interior fully written by fill) ---
    {
        const __half2 z2 = __float22half2_rn(make_float2(0.f, 0.f));
        // edge: pad rows 0,1 (entries 0..199) and 98,99 (9800..9999)
        if (tid < 400) sE[(tid < 200) ? tid : (9600 + tid)] = z2;
        // edge: interior pad rows 2..97, cols {0, 98, 99}
        if (tid < 288) {
            int r = tid / 3;
            int k = tid - 3 * r;
            int c = (k == 0) ? 0 : (97 + k);          // {0, 98, 99}
            sE[(r + 2) * EPS + c] = z2;
        }
        // mask: pad rows 0,1 (0..99) and 98,99 (4900..4999)
        if (tid < 200) sM[(tid < 100) ? tid : (4800 + tid)] = z2;
        // mask: interior pad rows 2..97, cols {0, 49}
        if (tid < 192) {
            int r = tid >> 1;
            int c = (tid & 1) ? 49 : 0;
            sM[(r + 2) * MPS + c] = z2;
        }
    }

    // --- fill interiors (disjoint from zeroed entries; no barrier needed) ---
    {
        const float* ebase = edge + (size_t)b * Hh * Ww;
        const float* mbase = mask + (size_t)b * Hh * Ww;
        for (int i = tid; i < Hh * (Ww / 2); i += THREADS) {
            int r = i / (Ww / 2);
            int j = i - r * (Ww / 2);
            const float* erow = ebase + r * Ww;
            float2 ae = *(const float2*)(erow + 2 * j);
            float ne = (2 * j + 2 < Ww) ? erow[2 * j + 2] : 0.f;
            int base = (r + 2) * EPS + 2 * j + 2;
            sE[base]     = __float22half2_rn(make_float2(ae.x, ae.y));
            sE[base + 1] = __float22half2_rn(make_float2(ae.y, ne));
            if (j == 0)
                sE[(r + 2) * EPS + 1] = __float22half2_rn(make_float2(0.f, ae.x));
            float2 am = *(const float2*)(mbase + r * Ww + 2 * j);
            sM[(r + 2) * MPS + 1 + j] = __float22half2_rn(make_float2(am.x, am.y));
        }
    }
    __syncthreads();

    // --- per-corner work: 6 LDS instructions per corner ---
    float eAcc = 0.f, mAcc = 0.f;
#pragma unroll
    for (int jj = 0; jj < PER_THREAD; ++jj) {
        float cx = (jj & 1) ? ((jj & 2) ? cc[jj >> 1].z : cc[jj >> 1].z)
                            : cc[jj >> 1].x;
        float cy;
        if (jj & 1) { cx = cc[jj >> 1].z; cy = cc[jj >> 1].w; }
        else        { cx = cc[jj >> 1].x; cy = cc[jj >> 1].y; }
        // ix = ((gx+1)*W - 1)*0.5 with gx = 2*cx - 1  ==>  ix = 96*cx - 0.5
        float ix = fmaf(cx, 96.f, -0.5f);
        float iy = fmaf(cy, 96.f, -0.5f);
        float x0f = floorf(ix), y0f = floorf(iy);
        float wx = ix - x0f, wy = iy - y0f;
        int x0 = (int)x0f, y0 = (int)y0f;

        // edge patch: pad rows y0+1..y0+4, entry cols x0+1 and x0+3
        int cb = (y0 + 1) * EPS + (x0 + 1);
        __half2 e00 = sE[cb],           e01 = sE[cb + 2];
        __half2 e10 = sE[cb + EPS],     e11 = sE[cb + EPS + 2];
        __half2 e20 = sE[cb + 2 * EPS], e21 = sE[cb + 2 * EPS + 2];
        __half2 e30 = sE[cb + 3 * EPS], e31 = sE[cb + 3 * EPS + 2];

        // mask 2x2: padded px p = x0+2, rows y0+2, y0+3
        int e0  = (x0 + 2) >> 1;
        int odd = x0 & 1;                  // (x0+2)&1 == x0&1
        int mb  = (y0 + 2) * MPS + e0;
        __half2 ma_lo = sM[mb],       ma_hi = sM[mb + 1];
        __half2 mc_lo = sM[mb + MPS], mc_hi = sM[mb + MPS + 1];

        float2 r00 = __half22float2(e00), r01 = __half22float2(e01);
        float2 r10 = __half22float2(e10), r11 = __half22float2(e11);
        float2 r20 = __half22float2(e20), r21 = __half22float2(e21);
        float2 r30 = __half22float2(e30), r31 = __half22float2(e31);

        float h[4][3];
        h[0][0] = fmaf(wx, r00.y - r00.x, r00.x);
        h[0][1] = fmaf(wx, r01.x - r00.y, r00.y);
        h[0][2] = fmaf(wx, r01.y - r01.x, r01.x);
        h[1][0] = fmaf(wx, r10.y - r10.x, r10.x);
        h[1][1] = fmaf(wx, r11.x - r10.y, r10.y);
        h[1][2] = fmaf(wx, r11.y - r11.x, r11.x);
        h[2][0] = fmaf(wx, r20.y - r20.x, r20.x);
        h[2][1] = fmaf(wx, r21.x - r20.y, r20.y);
        h[2][2] = fmaf(wx, r21.y - r21.x, r21.x);
        h[3][0] = fmaf(wx, r30.y - r30.x, r30.x);
        h[3][1] = fmaf(wx, r31.x - r30.y, r30.y);
        h[3][2] = fmaf(wx, r31.y - r31.x, r31.x);

        float best = fmaf(wy, h[1][0] - h[0][0], h[0][0]);
#pragma unroll
        for (int r = 0; r < 3; ++r) {
#pragma unroll
            for (int k = 0; k < 3; ++k) {
                if (r == 0 && k == 0) continue;
                float s = fmaf(wy, h[r + 1][k] - h[r][k], h[r][k]);
                best = fmaxf(best, s);
            }
        }
        eAcc += best;

        float2 qa = __half22float2(ma_lo), qb = __half22float2(ma_hi);
        float2 qc = __half22float2(mc_lo), qd = __half22float2(mc_hi);
        float l0 = odd ? qa.y : qa.x;
        float r0 = odd ? qb.x : qa.y;
        float l1 = odd ? qc.y : qc.x;
        float r1 = odd ? qd.x : qc.y;
        float t = fmaf(wx, r0 - l0, l0);
        float u = fmaf(wx, r1 - l1, l1);
        float m = fmaf(wy, u - t, t);
        float d = m - 0.5f;
        mAcc = fmaf(d, d, mAcc);
    }

    // --- reduce: wave shuffle, cross-wave via LDS, write per-block partial ---
#pragma unroll
    for (int off = 32; off > 0; off >>= 1) {
        eAcc += __shfl_xor(eAcc, off);
        mAcc += __shfl_xor(mAcc, off);
    }
    const int wv = tid >> 6;
    const int ln = tid & 63;
    if (ln == 0) { redE[wv] = eAcc; redM[wv] = mAcc; }
    __syncthreads();

    if (tid == 0) {
        float e = 0.f, m = 0.f;
#pragma unroll
        for (int w = 0; w < THREADS / 64; ++w) { e += redE[w]; m += redM[w]; }
        partial[blockIdx.x] = make_float2(e, m);
    }
}

// Final reduction over the 512 block partials; no atomics anywhere.
__global__ __launch_bounds__(512)
void geo_reduce(const float2* __restrict__ partial, float* __restrict__ out)
{
    __shared__ double rE[8];
    __shared__ double rM[8];
    const int tid = threadIdx.x;
    float2 p = partial[tid];               // 512 partials, 512 threads
    double e = (double)p.x, m = (double)p.y;
#pragma unroll
    for (int off = 32; off > 0; off >>= 1) {
        e += __shfl_xor(e, off);
        m += __shfl_xor(m, off);
    }
    if ((tid & 63) == 0) { rE[tid >> 6] = e; rM[tid >> 6] = m; }
    __syncthreads();
    if (tid == 0) {
        double se = 0.0, sm = 0.0;
#pragma unroll
        for (int w = 0; w < 8; ++w) { se += rE[w]; sm += rM[w]; }
        const double inv = 1.0 / (double)((long long)Bn * (long long)Nn);
        double edge_loss = 1.0 - se * inv;
        double mask_loss = sm * inv;
        out[0] = (float)(edge_loss + 2.0 * mask_loss);
    }
}

extern "C" void kernel_launch(void* const* d_in, const int* in_sizes, int n_in,
                              void* d_out, int out_size, void* d_ws, size_t ws_size,
                              hipStream_t stream)
{
    const float* corners = (const float*)d_in[0];
    const float* edge    = (const float*)d_in[1];
    const float* mask    = (const float*)d_in[2];
    float* out      = (float*)d_out;
    float2* partial = (float2*)d_ws;

    geo_kernel<<<Bn * CHUNKS, THREADS, 0, stream>>>(corners, edge, mask, partial);
    geo_reduce<<<1, 512, 0, stream>>>(partial, out);
}